// Round 6
// baseline (254.499 us; speedup 1.0000x reference)
//
#include <hip/hip_runtime.h>
#include <math.h>

// FundusQuantumLayer: 4-qubit, 3-layer variational circuit, batch 2^20.
// ev[q] = sum_{P in {I,Z,X}^4} C[q][P] * prod_r w_{P_r}(x_r), w = (1,cos x,sin x).
// Kernel 1 builds C (4x81) once; kernel 2 streams samples.
// Measured history: SPT=4 unconstrained -> 252 VGPR, 2 waves/SIMD, 44us (R4).
//                   cap 128 (launch_bounds(256,4)) -> forced spill, 790MB scratch
//                   traffic, 195us (R5). Natural live set ~150 VGPR.
// This round: SPT=4 + cap 170 (launch_bounds(256,3)) -> 3 waves/SIMD, no spill.

#define SPT 4   // samples per thread

__global__ void fq_setup(const float* __restrict__ w, float4* __restrict__ Ct) {
    __shared__ float2 sU[16][16];      // U[row][col] (re,im) of shared block
    __shared__ float  sReM[4][16][16]; // Re(U^dag Z_q U)
    const int tid = threadIdx.x;

    // ---- Stage A: simulate shared block; thread (r,c) holds U[r][c].
    {
        const int r = tid & 15, c = tid >> 4;
        float ar = (r == c) ? 1.f : 0.f, ai = 0.f;
#pragma unroll
        for (int l = 0; l < 3; ++l) {
#pragma unroll
            for (int q = 0; q < 4; ++q) {
                const int m = 1 << (3 - q);          // qubit 0 = MSB
                {   // RY(w[l][q][0])
                    float th = w[(l*4 + q)*2 + 0];
                    float cg = __cosf(0.5f*th), sg = __sinf(0.5f*th);
                    float obr = __shfl_xor(ar, m, 64);
                    float obi = __shfl_xor(ai, m, 64);
                    float t2 = (r & m) ? sg : -sg;
                    ar = cg*ar + t2*obr;
                    ai = cg*ai + t2*obi;
                }
                {   // RZ(w[l][q][1])
                    float ph = w[(l*4 + q)*2 + 1];
                    float cp = __cosf(0.5f*ph), sp = __sinf(0.5f*ph);
                    float t2 = (r & m) ? sp : -sp;
                    float nr = cp*ar - t2*ai;
                    float ni = cp*ai + t2*ar;
                    ar = nr; ai = ni;
                }
            }
            // CNOT ring (0,1),(1,2),(2,3),(3,0)
#pragma unroll
            for (int e = 0; e < 4; ++e) {
                const int mc = 1 << (3 - e);
                const int mt = 1 << (3 - ((e + 1) & 3));
                float obr = __shfl_xor(ar, mt, 64);
                float obi = __shfl_xor(ai, mt, 64);
                if (r & mc) { ar = obr; ai = obi; }
            }
        }
        sU[r][c] = make_float2(ar, ai);
    }
    __syncthreads();

    // ---- Stage B: ReM[q][i][j] = sum_k z_q(k) Re(conj(U[k][i]) U[k][j])
    {
        const int i = tid >> 4, j = tid & 15;
        float s0 = 0.f, s1 = 0.f, s2 = 0.f, s3 = 0.f;
#pragma unroll
        for (int k = 0; k < 16; ++k) {
            float2 uik = sU[k][i], ujk = sU[k][j];
            float pr = uik.x*ujk.x + uik.y*ujk.y;
            s0 += (k & 8) ? -pr : pr;
            s1 += (k & 4) ? -pr : pr;
            s2 += (k & 2) ? -pr : pr;
            s3 += (k & 1) ? -pr : pr;
        }
        sReM[0][i][j] = s0; sReM[1][i][j] = s1;
        sReM[2][i][j] = s2; sReM[3][i][j] = s3;
    }
    __syncthreads();

    // ---- Stage C: Ct[k81].q = tr(M_q P_{k81})/16, digits: 0=I 1=Z 2=X
    for (int idx = tid; idx < 324; idx += 256) {
        int q = idx / 81, k81 = idx % 81;
        int p0 = k81/27, p1 = (k81/9)%3, p2 = (k81/3)%3, p3 = k81%3;
        int xm = 0, zm = 0;
        if (p0 == 1) zm |= 8; else if (p0 == 2) xm |= 8;
        if (p1 == 1) zm |= 4; else if (p1 == 2) xm |= 4;
        if (p2 == 1) zm |= 2; else if (p2 == 2) xm |= 2;
        if (p3 == 1) zm |= 1; else if (p3 == 2) xm |= 1;
        float sum = 0.f;
#pragma unroll
        for (int j = 0; j < 16; ++j) {
            float sgn = (__popc(j & zm) & 1) ? -1.f : 1.f;
            sum += sgn * sReM[q][j ^ xm][j];
        }
        ((float*)Ct)[k81*4 + q] = sum * 0.0625f;
    }
}

__global__ __launch_bounds__(256, 3) void fq_main(const float4* __restrict__ x,
                                                  const float4* __restrict__ Ct,
                                                  float4* __restrict__ out) {
    __shared__ float4 sCt[81];
    const int tid = threadIdx.x;
    if (tid < 81) sCt[tid] = Ct[tid];
    __syncthreads();

    const int t0 = blockIdx.x * 256 + tid;
    const int NT = gridDim.x * 256;            // samples strided by NT

    float g01[SPT][9], g23[SPT][9];
    float acc[SPT][4];

#pragma unroll
    for (int s = 0; s < SPT; ++s) {
        float4 xv = x[t0 + s*NT];
        float c0 = __cosf(xv.x), s0 = __sinf(xv.x);
        float c1 = __cosf(xv.y), s1 = __sinf(xv.y);
        float c2 = __cosf(xv.z), s2 = __sinf(xv.z);
        float c3 = __cosf(xv.w), s3 = __sinf(xv.w);
        float f0[3] = {1.f, c0, s0}, f1[3] = {1.f, c1, s1};
        float f2[3] = {1.f, c2, s2}, f3[3] = {1.f, c3, s3};
#pragma unroll
        for (int a = 0; a < 3; ++a)
#pragma unroll
            for (int b = 0; b < 3; ++b) {
                g01[s][a*3+b] = f0[a] * f1[b];
                g23[s][a*3+b] = f2[a] * f3[b];
            }
#pragma unroll
        for (int q = 0; q < 4; ++q) acc[s][q] = 0.f;
    }

#pragma unroll
    for (int a = 0; a < 9; ++a) {
        float t[SPT][4];
#pragma unroll
        for (int s = 0; s < SPT; ++s)
#pragma unroll
            for (int q = 0; q < 4; ++q) t[s][q] = 0.f;
#pragma unroll
        for (int b = 0; b < 9; ++b) {
            float4 c = sCt[a*9 + b];           // same-addr ds_read_b128 broadcast
#pragma unroll
            for (int s = 0; s < SPT; ++s) {
                float g = g23[s][b];
                t[s][0] = fmaf(c.x, g, t[s][0]);
                t[s][1] = fmaf(c.y, g, t[s][1]);
                t[s][2] = fmaf(c.z, g, t[s][2]);
                t[s][3] = fmaf(c.w, g, t[s][3]);
            }
        }
#pragma unroll
        for (int s = 0; s < SPT; ++s) {
            float g = g01[s][a];
#pragma unroll
            for (int q = 0; q < 4; ++q)
                acc[s][q] = fmaf(t[s][q], g, acc[s][q]);
        }
    }

#pragma unroll
    for (int s = 0; s < SPT; ++s)
        out[t0 + s*NT] = make_float4(acc[s][0], acc[s][1], acc[s][2], acc[s][3]);
}

extern "C" void kernel_launch(void* const* d_in, const int* in_sizes, int n_in,
                              void* d_out, int out_size, void* d_ws, size_t ws_size,
                              hipStream_t stream) {
    const float* x = (const float*)d_in[0];     // [B,4] f32
    const float* w = (const float*)d_in[1];     // [3,4,2] f32
    float4* Ct = (float4*)d_ws;                 // 81 float4 scratch

    fq_setup<<<1, 256, 0, stream>>>(w, Ct);

    const int B = in_sizes[0] / 4;              // 1048576
    const int threads = B / SPT;                // 262144
    fq_main<<<threads / 256, 256, 0, stream>>>((const float4*)x, Ct, (float4*)d_out);
}

// Round 7
// 20.650 us; speedup vs baseline: 12.3244x; 12.3244x over previous
//
#include <hip/hip_runtime.h>
#include <math.h>

// FundusQuantumLayer: 4-qubit, 3-layer variational circuit, batch 2^20.
// ev[q] = sum_{P in {I,Z,X}^4} C[q][P] * prod_r w_{P_r}(x_r), w = (1,cos x,sin x).
// Kernel 1 builds C (4x81) once; kernel 2 streams samples.
//
// Measured history:
//  R4: SPT=4, LDS table, no cap      -> 252 VGPR, 2 waves/SIMD, ~40us (latency)
//  R5: cap 256/4=64  (lb(256,4))    -> spill, 790MB scratch, 195us
//  R6: cap 256/3=84  (lb(256,3))    -> spill, 790MB scratch, 254us
// Root cause: 81 wave-uniform float4 coefficients materialized in VGPRs.
// This round: coefficients via constant-address-space (AS4) pointer -> s_load
// -> SGPR-resident (0 VGPRs), SPT=1, no cap. SGPR file (102) self-limits
// hoisting; v_fma takes the coefficient as its one scalar operand.

typedef float f4 __attribute__((ext_vector_type(4)));
typedef const f4 __attribute__((address_space(4)))* c4ptr;  // constant AS -> s_load

__global__ void fq_setup(const float* __restrict__ w, float4* __restrict__ Ct) {
    __shared__ float2 sU[16][16];      // U[row][col] (re,im) of shared block
    __shared__ float  sReM[4][16][16]; // Re(U^dag Z_q U)
    const int tid = threadIdx.x;

    // ---- Stage A: simulate shared block; thread (r,c) holds U[r][c].
    {
        const int r = tid & 15, c = tid >> 4;
        float ar = (r == c) ? 1.f : 0.f, ai = 0.f;
#pragma unroll
        for (int l = 0; l < 3; ++l) {
#pragma unroll
            for (int q = 0; q < 4; ++q) {
                const int m = 1 << (3 - q);          // qubit 0 = MSB
                {   // RY(w[l][q][0])
                    float th = w[(l*4 + q)*2 + 0];
                    float cg = __cosf(0.5f*th), sg = __sinf(0.5f*th);
                    float obr = __shfl_xor(ar, m, 64);
                    float obi = __shfl_xor(ai, m, 64);
                    float t2 = (r & m) ? sg : -sg;
                    ar = cg*ar + t2*obr;
                    ai = cg*ai + t2*obi;
                }
                {   // RZ(w[l][q][1])
                    float ph = w[(l*4 + q)*2 + 1];
                    float cp = __cosf(0.5f*ph), sp = __sinf(0.5f*ph);
                    float t2 = (r & m) ? sp : -sp;
                    float nr = cp*ar - t2*ai;
                    float ni = cp*ai + t2*ar;
                    ar = nr; ai = ni;
                }
            }
            // CNOT ring (0,1),(1,2),(2,3),(3,0)
#pragma unroll
            for (int e = 0; e < 4; ++e) {
                const int mc = 1 << (3 - e);
                const int mt = 1 << (3 - ((e + 1) & 3));
                float obr = __shfl_xor(ar, mt, 64);
                float obi = __shfl_xor(ai, mt, 64);
                if (r & mc) { ar = obr; ai = obi; }
            }
        }
        sU[r][c] = make_float2(ar, ai);
    }
    __syncthreads();

    // ---- Stage B: ReM[q][i][j] = sum_k z_q(k) Re(conj(U[k][i]) U[k][j])
    {
        const int i = tid >> 4, j = tid & 15;
        float s0 = 0.f, s1 = 0.f, s2 = 0.f, s3 = 0.f;
#pragma unroll
        for (int k = 0; k < 16; ++k) {
            float2 uik = sU[k][i], ujk = sU[k][j];
            float pr = uik.x*ujk.x + uik.y*ujk.y;
            s0 += (k & 8) ? -pr : pr;
            s1 += (k & 4) ? -pr : pr;
            s2 += (k & 2) ? -pr : pr;
            s3 += (k & 1) ? -pr : pr;
        }
        sReM[0][i][j] = s0; sReM[1][i][j] = s1;
        sReM[2][i][j] = s2; sReM[3][i][j] = s3;
    }
    __syncthreads();

    // ---- Stage C: Ct[k81].q = tr(M_q P_{k81})/16, digits: 0=I 1=Z 2=X
    for (int idx = tid; idx < 324; idx += 256) {
        int q = idx / 81, k81 = idx % 81;
        int p0 = k81/27, p1 = (k81/9)%3, p2 = (k81/3)%3, p3 = k81%3;
        int xm = 0, zm = 0;
        if (p0 == 1) zm |= 8; else if (p0 == 2) xm |= 8;
        if (p1 == 1) zm |= 4; else if (p1 == 2) xm |= 4;
        if (p2 == 1) zm |= 2; else if (p2 == 2) xm |= 2;
        if (p3 == 1) zm |= 1; else if (p3 == 2) xm |= 1;
        float sum = 0.f;
#pragma unroll
        for (int j = 0; j < 16; ++j) {
            float sgn = (__popc(j & zm) & 1) ? -1.f : 1.f;
            sum += sgn * sReM[q][j ^ xm][j];
        }
        ((float*)Ct)[k81*4 + q] = sum * 0.0625f;
    }
}

__global__ __launch_bounds__(256) void fq_main(const float4* __restrict__ x,
                                               const float* __restrict__ Ct,
                                               float4* __restrict__ out) {
    const int i = blockIdx.x * 256 + threadIdx.x;

    // Wave-uniform coefficient table through constant address space:
    // backend selects s_load_dwordx4 -> coefficients live in SGPRs (0 VGPR).
    c4ptr C = (c4ptr)(unsigned long long)Ct;

    float4 xv = x[i];
    float c0 = __cosf(xv.x), s0 = __sinf(xv.x);
    float c1 = __cosf(xv.y), s1 = __sinf(xv.y);
    float c2 = __cosf(xv.z), s2 = __sinf(xv.z);
    float c3 = __cosf(xv.w), s3 = __sinf(xv.w);

    float f0[3] = {1.f, c0, s0}, f1[3] = {1.f, c1, s1};
    float f2[3] = {1.f, c2, s2}, f3[3] = {1.f, c3, s3};
    float g01[9], g23[9];
#pragma unroll
    for (int a = 0; a < 3; ++a)
#pragma unroll
        for (int b = 0; b < 3; ++b) {
            g01[a*3+b] = f0[a] * f1[b];        // [0] folds to 1.0f
            g23[a*3+b] = f2[a] * f3[b];
        }

    float a0 = 0.f, a1 = 0.f, a2 = 0.f, a3 = 0.f;
#pragma unroll
    for (int a = 0; a < 9; ++a) {
        float t0 = 0.f, t1 = 0.f, t2 = 0.f, t3 = 0.f;
#pragma unroll
        for (int b = 0; b < 9; ++b) {
            f4 c = C[a*9 + b];                 // s_load_dwordx4 (uniform addr)
            float g = g23[b];
            t0 = fmaf(c[0], g, t0);
            t1 = fmaf(c[1], g, t1);
            t2 = fmaf(c[2], g, t2);
            t3 = fmaf(c[3], g, t3);
        }
        float g = g01[a];
        a0 = fmaf(t0, g, a0);
        a1 = fmaf(t1, g, a1);
        a2 = fmaf(t2, g, a2);
        a3 = fmaf(t3, g, a3);
    }

    out[i] = make_float4(a0, a1, a2, a3);
}

extern "C" void kernel_launch(void* const* d_in, const int* in_sizes, int n_in,
                              void* d_out, int out_size, void* d_ws, size_t ws_size,
                              hipStream_t stream) {
    const float* x = (const float*)d_in[0];     // [B,4] f32
    const float* w = (const float*)d_in[1];     // [3,4,2] f32
    float4* Ct = (float4*)d_ws;                 // 81 float4 scratch

    fq_setup<<<1, 256, 0, stream>>>(w, Ct);

    const int B = in_sizes[0] / 4;              // 1048576
    fq_main<<<B / 256, 256, 0, stream>>>((const float4*)x, (const float*)Ct,
                                         (float4*)d_out);
}